// Round 1
// baseline (870.438 us; speedup 1.0000x reference)
//
#include <hip/hip_runtime.h>
#include <math.h>

#define S 1024
#define DIMM 1024
#define G 4
#define HPG 4
#define HD 64
#define PW 32
#define SCALE 0.125f
#define LNEPS 1e-5f

// ---------------- GEMM: C[M,N] = A[M,K] @ W[N,K]^T + bias[N] ----------------
// 64x64 tile, 256 threads, 4x4 microtile, K-step 16.
__global__ __launch_bounds__(256)
void gemm_bias(const float* __restrict__ A, const float* __restrict__ W,
               const float* __restrict__ bias, float* __restrict__ C,
               int M, int N, int K) {
    __shared__ float As[64][20];   // pad to 20 floats (80B) -> 16B-aligned rows
    __shared__ float Ws[64][20];
    const int tid = threadIdx.x;
    const int tx = tid & 15, ty = tid >> 4;
    const int m0 = blockIdx.y * 64, n0 = blockIdx.x * 64;
    const int lrow = tid >> 2, lq = (tid & 3) * 4;
    const float* Ap = A + (size_t)(m0 + lrow) * K + lq;
    const float* Wp = W + (size_t)(n0 + lrow) * K + lq;
    float acc[4][4] = {};
    for (int k0 = 0; k0 < K; k0 += 16) {
        __syncthreads();
        *(float4*)&As[lrow][lq] = *(const float4*)(Ap + k0);
        *(float4*)&Ws[lrow][lq] = *(const float4*)(Wp + k0);
        __syncthreads();
        #pragma unroll
        for (int kb = 0; kb < 4; ++kb) {
            float4 a[4], w[4];
            #pragma unroll
            for (int i = 0; i < 4; ++i) a[i] = *(const float4*)&As[ty + 16*i][kb*4];
            #pragma unroll
            for (int j = 0; j < 4; ++j) w[j] = *(const float4*)&Ws[tx + 16*j][kb*4];
            #pragma unroll
            for (int i = 0; i < 4; ++i) {
                #pragma unroll
                for (int j = 0; j < 4; ++j) {
                    acc[i][j] += a[i].x*w[j].x + a[i].y*w[j].y
                               + a[i].z*w[j].z + a[i].w*w[j].w;
                }
            }
        }
    }
    #pragma unroll
    for (int i = 0; i < 4; ++i) {
        const int m = m0 + ty + 16*i;
        #pragma unroll
        for (int j = 0; j < 4; ++j) {
            const int n = n0 + tx + 16*j;
            C[(size_t)m * N + n] = acc[i][j] + bias[n];
        }
    }
}

// ---------------- wave-wide helpers ----------------
__device__ inline float wave64_sum(float v) {
    #pragma unroll
    for (int off = 32; off >= 1; off >>= 1) v += __shfl_xor(v, off);
    return v;
}

// ---------------- q: LayerNorm + rotary, write [bgh][s][d] ----------------
// one wave (64 lanes) per (bgh, s) row; 4 rows per block
__global__ __launch_bounds__(256)
void q_transform(const float* __restrict__ q_lin, const float* __restrict__ gam,
                 const float* __restrict__ bet, const int* __restrict__ t_id,
                 float* __restrict__ q_n) {
    const int row  = blockIdx.x * 4 + (threadIdx.x >> 6);  // bgh*S + s
    const int lane = threadIdx.x & 63;
    const int s    = row & (S - 1);
    const int bgh  = row >> 10;
    const int b    = bgh >> 4;
    const int gh   = bgh & 15;
    float x = q_lin[(size_t)(b * S + s) * DIMM + gh * HD + lane];
    const float m = wave64_sum(x) * (1.0f / 64.0f);
    const float d = x - m;
    const float v = wave64_sum(d * d) * (1.0f / 64.0f);
    float y = d * rsqrtf(v + LNEPS) * gam[lane] + bet[lane];
    const float partner = __shfl_xor(y, 1);
    if (lane < PW) {
        const int i = lane >> 1;                       // theta index 0..15
        const float theta = expf(-0.57564627324851f * (float)i); // 10000^(-i/16)
        const float ang = (float)t_id[b * S + s] * theta;
        const float cs = cosf(ang), sn = sinf(ang);
        y = cs * y + sn * ((lane & 1) ? partner : -partner);
    }
    q_n[(size_t)row * HD + lane] = y;
}

// ---------------- k: LayerNorm + rotary, write [bg][s][d] ----------------
__global__ __launch_bounds__(256)
void k_transform(const float* __restrict__ k_lin, const float* __restrict__ gam,
                 const float* __restrict__ bet, const int* __restrict__ t_id,
                 float* __restrict__ k_n) {
    const int row  = blockIdx.x * 4 + (threadIdx.x >> 6);  // bg*S + s
    const int lane = threadIdx.x & 63;
    const int s    = row & (S - 1);
    const int bg   = row >> 10;
    const int b    = bg >> 2;
    const int g    = bg & 3;
    float x = k_lin[(size_t)(b * S + s) * (G * HD) + g * HD + lane];
    const float m = wave64_sum(x) * (1.0f / 64.0f);
    const float d = x - m;
    const float v = wave64_sum(d * d) * (1.0f / 64.0f);
    float y = d * rsqrtf(v + LNEPS) * gam[lane] + bet[lane];
    const float partner = __shfl_xor(y, 1);
    if (lane < PW) {
        const int i = lane >> 1;
        const float theta = expf(-0.57564627324851f * (float)i);
        const float ang = (float)t_id[b * S + s] * theta;
        const float cs = cosf(ang), sn = sinf(ang);
        y = cs * y + sn * ((lane & 1) ? partner : -partner);
    }
    k_n[(size_t)row * HD + lane] = y;
}

// ---------------- flash attention, f32 ----------------
// block = 256 threads, handles (bgh, 32 q-rows); k-tiles of 32, online softmax.
__global__ __launch_bounds__(256)
void flash_attn(const float* __restrict__ q_n, const float* __restrict__ k_n,
                const float* __restrict__ v_lin, const float* __restrict__ var_emb,
                const int* __restrict__ qvar, const int* __restrict__ kvar,
                float* __restrict__ attn) {
    __shared__ float Qs[32][68];
    __shared__ float Ks[32][68];
    __shared__ float Vs[32][68];
    __shared__ float Ss[32][33];
    __shared__ int   kvs[32];
    __shared__ int   qvs[32];

    const int tid = threadIdx.x;
    const int qb  = blockIdx.x & 31;
    const int bgh = blockIdx.x >> 5;
    const int b   = bgh >> 4;
    const int g   = (bgh >> 2) & 3;
    const int gh  = bgh & 15;

    const int r  = tid >> 3;      // q-row 0..31 (also k-row / v-row when staging)
    const int u  = tid & 7;       // 0..7
    const int c8 = u * 8;

    const float* qbase = q_n + ((size_t)bgh * S + qb * 32) * HD;
    const float* kbase = k_n + (size_t)(b * G + g) * S * HD;
    const float* vbase = v_lin + (size_t)b * S * (G * HD) + g * HD;

    *(float4*)&Qs[r][c8]     = *(const float4*)(qbase + r * HD + c8);
    *(float4*)&Qs[r][c8 + 4] = *(const float4*)(qbase + r * HD + c8 + 4);
    if (tid < 32) qvs[tid] = qvar[b * S + qb * 32 + tid];

    const float w0 = var_emb[gh];
    const float w1 = var_emb[16 + gh];

    float O[8] = {0, 0, 0, 0, 0, 0, 0, 0};
    float mrun = -1e30f, lrun = 0.0f;

    for (int kt = 0; kt < 32; ++kt) {
        const int k0 = kt * 32;
        __syncthreads();   // previous PV done: safe to overwrite Ks/Vs/kvs
        *(float4*)&Ks[r][c8]     = *(const float4*)(kbase + (k0 + r) * HD + c8);
        *(float4*)&Ks[r][c8 + 4] = *(const float4*)(kbase + (k0 + r) * HD + c8 + 4);
        *(float4*)&Vs[r][c8]     = *(const float4*)(vbase + (size_t)(k0 + r) * (G * HD) + c8);
        *(float4*)&Vs[r][c8 + 4] = *(const float4*)(vbase + (size_t)(k0 + r) * (G * HD) + c8 + 4);
        if (tid < 32) kvs[tid] = kvar[b * S + k0 + tid];
        __syncthreads();

        // scores: row r, cols u + 8j
        float dots[4] = {0, 0, 0, 0};
        const float4* qr = (const float4*)&Qs[r][0];
        #pragma unroll
        for (int d4 = 0; d4 < 16; ++d4) {
            const float4 qv4 = qr[d4];
            #pragma unroll
            for (int j = 0; j < 4; ++j) {
                const float4 kv4 = *(const float4*)&Ks[u + 8*j][d4 * 4];
                dots[j] += qv4.x*kv4.x + qv4.y*kv4.y + qv4.z*kv4.z + qv4.w*kv4.w;
            }
        }
        const int qv_id = qvs[r];
        float sc[4];
        float tmax = -1e30f;
        #pragma unroll
        for (int j = 0; j < 4; ++j) {
            sc[j] = dots[j] * SCALE + ((qv_id == kvs[u + 8*j]) ? w1 : w0);
            tmax = fmaxf(tmax, sc[j]);
        }
        tmax = fmaxf(tmax, __shfl_xor(tmax, 1));
        tmax = fmaxf(tmax, __shfl_xor(tmax, 2));
        tmax = fmaxf(tmax, __shfl_xor(tmax, 4));
        const float mnew  = fmaxf(mrun, tmax);
        const float alpha = expf(mrun - mnew);
        float psum = 0.0f;
        #pragma unroll
        for (int j = 0; j < 4; ++j) {
            const float p = expf(sc[j] - mnew);
            Ss[r][u + 8*j] = p;
            psum += p;
        }
        psum += __shfl_xor(psum, 1);
        psum += __shfl_xor(psum, 2);
        psum += __shfl_xor(psum, 4);
        lrun = lrun * alpha + psum;
        mrun = mnew;
        #pragma unroll
        for (int e = 0; e < 8; ++e) O[e] *= alpha;
        __syncthreads();

        // PV: O[r][c8..c8+7] += P[r][kk] * V[kk][c8..c8+7]
        #pragma unroll 8
        for (int kk = 0; kk < 32; ++kk) {
            const float p = Ss[r][kk];
            const float4 v0 = *(const float4*)&Vs[kk][c8];
            const float4 v1 = *(const float4*)&Vs[kk][c8 + 4];
            O[0] += p*v0.x; O[1] += p*v0.y; O[2] += p*v0.z; O[3] += p*v0.w;
            O[4] += p*v1.x; O[5] += p*v1.y; O[6] += p*v1.z; O[7] += p*v1.w;
        }
    }

    const float inv = 1.0f / lrun;
    float* op = attn + (size_t)(b * S + qb * 32 + r) * DIMM + gh * HD + c8;
    float4 o0 = make_float4(O[0]*inv, O[1]*inv, O[2]*inv, O[3]*inv);
    float4 o1 = make_float4(O[4]*inv, O[5]*inv, O[6]*inv, O[7]*inv);
    *(float4*)op       = o0;
    *(float4*)(op + 4) = o1;
}

extern "C" void kernel_launch(void* const* d_in, const int* in_sizes, int n_in,
                              void* d_out, int out_size, void* d_ws, size_t ws_size,
                              hipStream_t stream) {
    const float* x     = (const float*)d_in[0];
    const float* kv    = (const float*)d_in[1];
    const float* q_w   = (const float*)d_in[2];
    const float* q_b   = (const float*)d_in[3];
    const float* k_w   = (const float*)d_in[4];
    const float* k_b   = (const float*)d_in[5];
    const float* v_w   = (const float*)d_in[6];
    const float* v_b   = (const float*)d_in[7];
    const float* o_w   = (const float*)d_in[8];
    const float* o_b   = (const float*)d_in[9];
    const float* qn_g  = (const float*)d_in[10];
    const float* qn_b  = (const float*)d_in[11];
    const float* kn_g  = (const float*)d_in[12];
    const float* kn_b  = (const float*)d_in[13];
    const float* vemb  = (const float*)d_in[14];
    const int*   qvar  = (const int*)d_in[15];
    const int*   kvar  = (const int*)d_in[16];
    const int*   qtime = (const int*)d_in[17];
    const int*   ktime = (const int*)d_in[18];
    float* out = (float*)d_out;
    float* ws  = (float*)d_ws;

    // ws layout (floats):
    float* q_lin = ws;              // 4M  (dead after q_transform)
    float* k_lin = ws + 4194304;    // 1M
    float* v_lin = ws + 5242880;    // 1M  (read by flash directly)
    float* q_n   = ws + 6291456;    // 4M
    float* k_n   = ws + 10485760;   // 1M
    float* attn  = ws;              // 4M  (reuses q_lin region)

    const int M = 4 * S;            // 4096
    dim3 blk(256);

    gemm_bias<<<dim3(DIMM/64, M/64), blk, 0, stream>>>(x,  q_w, q_b, q_lin, M, DIMM, DIMM);
    gemm_bias<<<dim3((G*HD)/64, M/64), blk, 0, stream>>>(kv, k_w, k_b, k_lin, M, G*HD, DIMM);
    gemm_bias<<<dim3((G*HD)/64, M/64), blk, 0, stream>>>(kv, v_w, v_b, v_lin, M, G*HD, DIMM);

    q_transform<<<(4 * G * HPG * S) / 4, blk, 0, stream>>>(q_lin, qn_g, qn_b, qtime, q_n);
    k_transform<<<(4 * G * S) / 4,       blk, 0, stream>>>(k_lin, kn_g, kn_b, ktime, k_n);

    flash_attn<<<4 * G * HPG * (S / 32), blk, 0, stream>>>(q_n, k_n, v_lin, vemb, qvar, kvar, attn);

    gemm_bias<<<dim3(DIMM/64, M/64), blk, 0, stream>>>(attn, o_w, o_b, out, M, DIMM, DIMM);
}

// Round 2
// 594.607 us; speedup vs baseline: 1.4639x; 1.4639x over previous
//
#include <hip/hip_runtime.h>
#include <math.h>

#define S 1024
#define DIMM 1024
#define G 4
#define HPG 4
#define HD 64
#define PW 32
#define SCALE 0.125f
#define LNEPS 1e-5f

typedef __bf16 bf16x8 __attribute__((ext_vector_type(8)));
typedef float  f32x4  __attribute__((ext_vector_type(4)));

// ---------------- GEMM: C[M,N] = A[M,K] @ W[N,K]^T + bias[N] ----------------
__global__ __launch_bounds__(256)
void gemm_bias(const float* __restrict__ A, const float* __restrict__ W,
               const float* __restrict__ bias, float* __restrict__ C,
               int M, int N, int K) {
    __shared__ float As[64][20];
    __shared__ float Ws[64][20];
    const int tid = threadIdx.x;
    const int tx = tid & 15, ty = tid >> 4;
    const int m0 = blockIdx.y * 64, n0 = blockIdx.x * 64;
    const int lrow = tid >> 2, lq = (tid & 3) * 4;
    const float* Ap = A + (size_t)(m0 + lrow) * K + lq;
    const float* Wp = W + (size_t)(n0 + lrow) * K + lq;
    float acc[4][4] = {};
    for (int k0 = 0; k0 < K; k0 += 16) {
        __syncthreads();
        *(float4*)&As[lrow][lq] = *(const float4*)(Ap + k0);
        *(float4*)&Ws[lrow][lq] = *(const float4*)(Wp + k0);
        __syncthreads();
        #pragma unroll
        for (int kb = 0; kb < 4; ++kb) {
            float4 a[4], w[4];
            #pragma unroll
            for (int i = 0; i < 4; ++i) a[i] = *(const float4*)&As[ty + 16*i][kb*4];
            #pragma unroll
            for (int j = 0; j < 4; ++j) w[j] = *(const float4*)&Ws[tx + 16*j][kb*4];
            #pragma unroll
            for (int i = 0; i < 4; ++i)
                #pragma unroll
                for (int j = 0; j < 4; ++j)
                    acc[i][j] += a[i].x*w[j].x + a[i].y*w[j].y
                               + a[i].z*w[j].z + a[i].w*w[j].w;
        }
    }
    #pragma unroll
    for (int i = 0; i < 4; ++i) {
        const int m = m0 + ty + 16*i;
        #pragma unroll
        for (int j = 0; j < 4; ++j) {
            const int n = n0 + tx + 16*j;
            C[(size_t)m * N + n] = acc[i][j] + bias[n];
        }
    }
}

__device__ inline float wave64_sum(float v) {
    #pragma unroll
    for (int off = 32; off >= 1; off >>= 1) v += __shfl_xor(v, off);
    return v;
}

// ---------------- q: LayerNorm + rotary -> bf16 [bgh][s][d] ----------------
__global__ __launch_bounds__(256)
void q_transform(const float* __restrict__ q_lin, const float* __restrict__ gam,
                 const float* __restrict__ bet, const int* __restrict__ t_id,
                 __bf16* __restrict__ q_n) {
    const int row  = blockIdx.x * 4 + (threadIdx.x >> 6);
    const int lane = threadIdx.x & 63;
    const int s    = row & (S - 1);
    const int bgh  = row >> 10;
    const int b    = bgh >> 4;
    const int gh   = bgh & 15;
    float x = q_lin[(size_t)(b * S + s) * DIMM + gh * HD + lane];
    const float m = wave64_sum(x) * (1.0f / 64.0f);
    const float d = x - m;
    const float v = wave64_sum(d * d) * (1.0f / 64.0f);
    float y = d * rsqrtf(v + LNEPS) * gam[lane] + bet[lane];
    const float partner = __shfl_xor(y, 1);
    if (lane < PW) {
        const int i = lane >> 1;
        const float theta = expf(-0.57564627324851f * (float)i);
        const float ang = (float)t_id[b * S + s] * theta;
        const float cs = cosf(ang), sn = sinf(ang);
        y = cs * y + sn * ((lane & 1) ? partner : -partner);
    }
    q_n[(size_t)row * HD + lane] = (__bf16)y;
}

// ---------------- k: LayerNorm + rotary -> bf16 [bg][s][d] ----------------
__global__ __launch_bounds__(256)
void k_transform(const float* __restrict__ k_lin, const float* __restrict__ gam,
                 const float* __restrict__ bet, const int* __restrict__ t_id,
                 __bf16* __restrict__ k_n) {
    const int row  = blockIdx.x * 4 + (threadIdx.x >> 6);
    const int lane = threadIdx.x & 63;
    const int s    = row & (S - 1);
    const int bg   = row >> 10;
    const int b    = bg >> 2;
    const int g    = bg & 3;
    float x = k_lin[(size_t)(b * S + s) * (G * HD) + g * HD + lane];
    const float m = wave64_sum(x) * (1.0f / 64.0f);
    const float d = x - m;
    const float v = wave64_sum(d * d) * (1.0f / 64.0f);
    float y = d * rsqrtf(v + LNEPS) * gam[lane] + bet[lane];
    const float partner = __shfl_xor(y, 1);
    if (lane < PW) {
        const int i = lane >> 1;
        const float theta = expf(-0.57564627324851f * (float)i);
        const float ang = (float)t_id[b * S + s] * theta;
        const float cs = cosf(ang), sn = sinf(ang);
        y = cs * y + sn * ((lane & 1) ? partner : -partner);
    }
    k_n[(size_t)row * HD + lane] = (__bf16)y;
}

// ---------------- V transpose: f32 [b][s][g*64+d] -> bf16 [bg][d][s] -------
__global__ __launch_bounds__(256)
void v_transpose(const float* __restrict__ v_lin, __bf16* __restrict__ vt) {
    __shared__ float T[64][65];
    const int bg = blockIdx.x >> 4;
    const int s0 = (blockIdx.x & 15) * 64;
    const int b = bg >> 2, g = bg & 3;
    const int tx = threadIdx.x & 63, ty = threadIdx.x >> 6;
    const float* src = v_lin + ((size_t)(b * S) + s0) * (G * HD) + g * HD;
    #pragma unroll
    for (int i = 0; i < 16; ++i) {
        const int sp = ty + 4 * i;
        T[sp][tx] = src[(size_t)sp * (G * HD) + tx];
    }
    __syncthreads();
    __bf16* dst = vt + (size_t)bg * HD * S + s0;
    #pragma unroll
    for (int i = 0; i < 16; ++i) {
        const int d = ty + 4 * i;
        dst[(size_t)d * S + tx] = (__bf16)T[tx][d];
    }
}

// ---------------- flash attention, bf16 MFMA ----------------
// block = 256 thr = 4 waves; each wave owns 16 q-rows, no intra-loop barriers.
__global__ __launch_bounds__(256)
void flash_mfma(const __bf16* __restrict__ q_n, const __bf16* __restrict__ k_n,
                const __bf16* __restrict__ vt, const float* __restrict__ var_emb,
                const int* __restrict__ qvar, const int* __restrict__ kvar,
                float* __restrict__ attn) {
    __shared__ float Ss[4][64][20];   // per-wave, col-major [col][row], 16B-aligned rows

    const int tid = threadIdx.x;
    const int w = tid >> 6, l = tid & 63;
    const int lr = l & 15, lh = l >> 4;
    const int qb = blockIdx.x & 15;
    const int bgh = blockIdx.x >> 4;
    const int b = bgh >> 4, gh = bgh & 15;
    const int bg = bgh >> 2;          // b*4+g

    const int q0 = qb * 64 + w * 16;

    // Q fragments (A-layout): lane holds Q[q0+lr][32h + 8*lh + e]
    const __bf16* qbase = q_n + ((size_t)bgh * S + q0 + lr) * HD + 8 * lh;
    const bf16x8 qa0 = *(const bf16x8*)(qbase);
    const bf16x8 qa1 = *(const bf16x8*)(qbase + 32);

    const int   qv = qvar[b * S + q0 + lr];
    const float w0 = var_emb[gh];
    const float w1 = var_emb[16 + gh];

    const __bf16* kbase = k_n + (size_t)bg * S * HD;
    const __bf16* vbase = vt + (size_t)bg * HD * S;
    const int* kvb = kvar + b * S;

    f32x4 O[4];
    #pragma unroll
    for (int t = 0; t < 4; ++t) O[t] = (f32x4){0.f, 0.f, 0.f, 0.f};
    float mrun = -1e30f, lrun = 0.0f;

    for (int k0 = 0; k0 < S; k0 += 64) {
        // ---- QK^T: 4 tiles of 16 k-cols, chained over d-halves ----
        f32x4 st[4];
        #pragma unroll
        for (int t = 0; t < 4; ++t) {
            const __bf16* kp = kbase + (size_t)(k0 + 16 * t + lr) * HD + 8 * lh;
            const bf16x8 kb0 = *(const bf16x8*)(kp);
            const bf16x8 kb1 = *(const bf16x8*)(kp + 32);
            f32x4 acc = (f32x4){0.f, 0.f, 0.f, 0.f};
            acc = __builtin_amdgcn_mfma_f32_16x16x32_bf16(qa0, kb0, acc, 0, 0, 0);
            acc = __builtin_amdgcn_mfma_f32_16x16x32_bf16(qa1, kb1, acc, 0, 0, 0);
            st[t] = acc;
        }
        // stage scores col-major: Ss[w][col][row], rows (4*lh..4*lh+3) = regs
        #pragma unroll
        for (int t = 0; t < 4; ++t)
            *(f32x4*)&Ss[w][16 * t + lr][4 * lh] = st[t];

        // ---- read back in A-layout (row = lr, k = 32c + 8*lh + e) + softmax ----
        float sv[2][8];
        float tmax = -1e30f;
        #pragma unroll
        for (int c = 0; c < 2; ++c) {
            int kvi[8];
            *(int4*)(&kvi[0]) = *(const int4*)(kvb + k0 + 32 * c + 8 * lh);
            *(int4*)(&kvi[4]) = *(const int4*)(kvb + k0 + 32 * c + 8 * lh + 4);
            #pragma unroll
            for (int e = 0; e < 8; ++e) {
                float sc = Ss[w][32 * c + 8 * lh + e][lr];
                sc = sc * SCALE + ((qv == kvi[e]) ? w1 : w0);
                sv[c][e] = sc;
                tmax = fmaxf(tmax, sc);
            }
        }
        tmax = fmaxf(tmax, __shfl_xor(tmax, 16));
        tmax = fmaxf(tmax, __shfl_xor(tmax, 32));
        const float mnew  = fmaxf(mrun, tmax);
        const float alpha = __expf(mrun - mnew);
        float psum = 0.0f;
        bf16x8 pa0, pa1;
        #pragma unroll
        for (int e = 0; e < 8; ++e) {
            const float p0 = __expf(sv[0][e] - mnew);
            const float p1 = __expf(sv[1][e] - mnew);
            psum += p0 + p1;
            pa0[e] = (__bf16)p0;
            pa1[e] = (__bf16)p1;
        }
        psum += __shfl_xor(psum, 16);
        psum += __shfl_xor(psum, 32);
        lrun = lrun * alpha + psum;
        mrun = mnew;

        // rescale O: row of O-reg r is 4*lh + r; its alpha lives in lane (4*lh+r)
        const float a0 = __shfl(alpha, 4 * lh + 0);
        const float a1 = __shfl(alpha, 4 * lh + 1);
        const float a2 = __shfl(alpha, 4 * lh + 2);
        const float a3 = __shfl(alpha, 4 * lh + 3);
        #pragma unroll
        for (int t = 0; t < 4; ++t) {
            O[t][0] *= a0; O[t][1] *= a1; O[t][2] *= a2; O[t][3] *= a3;
        }

        // ---- PV: O[16q x 64d] += P[16q x 64k] * V[64k x 64d] ----
        #pragma unroll
        for (int t = 0; t < 4; ++t) {
            const __bf16* vp = vbase + (size_t)(16 * t + lr) * S + k0 + 8 * lh;
            const bf16x8 vb0 = *(const bf16x8*)(vp);
            const bf16x8 vb1 = *(const bf16x8*)(vp + 32);
            O[t] = __builtin_amdgcn_mfma_f32_16x16x32_bf16(pa0, vb0, O[t], 0, 0, 0);
            O[t] = __builtin_amdgcn_mfma_f32_16x16x32_bf16(pa1, vb1, O[t], 0, 0, 0);
        }
    }

    const float l0 = 1.0f / __shfl(lrun, 4 * lh + 0);
    const float l1 = 1.0f / __shfl(lrun, 4 * lh + 1);
    const float l2 = 1.0f / __shfl(lrun, 4 * lh + 2);
    const float l3 = 1.0f / __shfl(lrun, 4 * lh + 3);
    #pragma unroll
    for (int t = 0; t < 4; ++t) {
        float* op = attn + ((size_t)(b * S + q0 + 4 * lh)) * DIMM + gh * HD + 16 * t + lr;
        op[0 * DIMM] = O[t][0] * l0;
        op[1 * DIMM] = O[t][1] * l1;
        op[2 * DIMM] = O[t][2] * l2;
        op[3 * DIMM] = O[t][3] * l3;
    }
}

extern "C" void kernel_launch(void* const* d_in, const int* in_sizes, int n_in,
                              void* d_out, int out_size, void* d_ws, size_t ws_size,
                              hipStream_t stream) {
    const float* x     = (const float*)d_in[0];
    const float* kv    = (const float*)d_in[1];
    const float* q_w   = (const float*)d_in[2];
    const float* q_b   = (const float*)d_in[3];
    const float* k_w   = (const float*)d_in[4];
    const float* k_b   = (const float*)d_in[5];
    const float* v_w   = (const float*)d_in[6];
    const float* v_b   = (const float*)d_in[7];
    const float* o_w   = (const float*)d_in[8];
    const float* o_b   = (const float*)d_in[9];
    const float* qn_g  = (const float*)d_in[10];
    const float* qn_b  = (const float*)d_in[11];
    const float* kn_g  = (const float*)d_in[12];
    const float* kn_b  = (const float*)d_in[13];
    const float* vemb  = (const float*)d_in[14];
    const int*   qvar  = (const int*)d_in[15];
    const int*   kvar  = (const int*)d_in[16];
    const int*   qtime = (const int*)d_in[17];
    const int*   ktime = (const int*)d_in[18];
    float* out = (float*)d_out;
    char*  W   = (char*)d_ws;

    float*  q_lin = (float*)(W);                    // 16 MB
    float*  k_lin = (float*)(W + (16u << 20));      //  4 MB
    float*  v_lin = (float*)(W + (20u << 20));      //  4 MB
    __bf16* q_nb  = (__bf16*)(W + (24u << 20));     //  8 MB
    __bf16* k_nb  = (__bf16*)(W + (32u << 20));     //  2 MB
    __bf16* vtb   = (__bf16*)(W + (34u << 20));     //  2 MB  (ends at 36 MB)
    float*  attn  = q_lin;                          // reuse (q_lin dead after q_transform)

    const int M = 4 * S;
    dim3 blk(256);

    gemm_bias<<<dim3(DIMM/64, M/64), blk, 0, stream>>>(x,  q_w, q_b, q_lin, M, DIMM, DIMM);
    gemm_bias<<<dim3((G*HD)/64, M/64), blk, 0, stream>>>(kv, k_w, k_b, k_lin, M, G*HD, DIMM);
    gemm_bias<<<dim3((G*HD)/64, M/64), blk, 0, stream>>>(kv, v_w, v_b, v_lin, M, G*HD, DIMM);

    q_transform<<<(4 * G * HPG * S) / 4, blk, 0, stream>>>(q_lin, qn_g, qn_b, qtime, q_nb);
    k_transform<<<(4 * G * S) / 4,       blk, 0, stream>>>(k_lin, kn_g, kn_b, ktime, k_nb);
    v_transpose<<<16 * 16,               blk, 0, stream>>>(v_lin, vtb);

    flash_mfma<<<4 * G * HPG * (S / 64), blk, 0, stream>>>(q_nb, k_nb, vtb, vemb, qvar, kvar, attn);

    gemm_bias<<<dim3(DIMM/64, M/64), blk, 0, stream>>>(attn, o_w, o_b, out, M, DIMM, DIMM);
}

// Round 3
// 273.241 us; speedup vs baseline: 3.1856x; 2.1761x over previous
//
#include <hip/hip_runtime.h>
#include <math.h>

#define S 1024
#define DIMM 1024
#define G 4
#define HPG 4
#define HD 64
#define PW 32
#define SCALE 0.125f
#define LNEPS 1e-5f

typedef __bf16 bf16x8 __attribute__((ext_vector_type(8)));
typedef float  f32x4  __attribute__((ext_vector_type(4)));

// ---------------- f32 -> bf16 (optionally hi/lo pair) ----------------
__global__ __launch_bounds__(256)
void cvt_bf16(const float* __restrict__ src, __bf16* __restrict__ hi,
              __bf16* __restrict__ lo, int n8) {
    const int i = blockIdx.x * 256 + threadIdx.x;
    if (i >= n8) return;
    const float4 a = *(const float4*)(src + (size_t)i * 8);
    const float4 b = *(const float4*)(src + (size_t)i * 8 + 4);
    const float v[8] = {a.x, a.y, a.z, a.w, b.x, b.y, b.z, b.w};
    bf16x8 H, L;
    #pragma unroll
    for (int e = 0; e < 8; ++e) H[e] = (__bf16)v[e];
    *(bf16x8*)(hi + (size_t)i * 8) = H;
    if (lo != nullptr) {
        #pragma unroll
        for (int e = 0; e < 8; ++e) L[e] = (__bf16)(v[e] - (float)H[e]);
        *(bf16x8*)(lo + (size_t)i * 8) = L;
    }
}

__global__ void concat_bias(const float* __restrict__ k_b, const float* __restrict__ v_b,
                            float* __restrict__ kvb) {
    const int t = threadIdx.x;
    kvb[t] = k_b[t];
    kvb[256 + t] = v_b[t];
}

// ---------------- bf16 MFMA GEMM: C[M,N] = A[M,K] @ W[N,K]^T + bias ----------------
// 128 x NB tile, 256 threads (4 waves), BK=32, global_load_lds staging (m97 structure).
__device__ __forceinline__ void gld_lds16(const __bf16* g, __bf16* lds) {
    __builtin_amdgcn_global_load_lds(
        (const __attribute__((address_space(1))) void*)g,
        (__attribute__((address_space(3))) void*)lds, 16, 0, 0);
}

template<int NB, bool SPLIT, bool OUTBF>
__global__ __launch_bounds__(256)
void gemm_mfma(const __bf16* __restrict__ Ah, const __bf16* __restrict__ Al,
               const __bf16* __restrict__ Wh, const __bf16* __restrict__ Wl,
               const float* __restrict__ bias, void* __restrict__ Cout,
               const int N, const int K) {
    constexpr int WN  = NB / 2;    // wave tile cols
    constexpr int FN  = WN / 16;   // col fragments per wave
    constexpr int NWC = NB / 16;   // W-tile 16-row chunks
    __shared__ __bf16 Ahs[128][32];
    __shared__ __bf16 Whs[NB][32];
    __shared__ __bf16 Als[SPLIT ? 128 : 1][32];
    __shared__ __bf16 Wls[SPLIT ? NB : 1][32];

    const int tid = threadIdx.x;
    const int w = tid >> 6, l = tid & 63;
    const int lr = l & 15, lh = l >> 4;
    const int wr = w >> 1, wc = w & 1;
    const int m0 = blockIdx.y * 128, n0 = blockIdx.x * NB;
    const int srow = l >> 2, scol = (l & 3) * 8;   // staging: 16 rows x 32 cols per 1KB chunk

    f32x4 acc[4][FN];
    #pragma unroll
    for (int i = 0; i < 4; ++i)
        #pragma unroll
        for (int j = 0; j < FN; ++j) acc[i][j] = (f32x4){0.f, 0.f, 0.f, 0.f};

    const __bf16* Abp = Ah + (size_t)(m0 + srow) * K + scol;
    const __bf16* Wbp = Wh + (size_t)(n0 + srow) * K + scol;
    const __bf16* Alp = SPLIT ? (Al + (size_t)(m0 + srow) * K + scol) : nullptr;
    const __bf16* Wlp = SPLIT ? (Wl + (size_t)(n0 + srow) * K + scol) : nullptr;

    for (int k0 = 0; k0 < K; k0 += 32) {
        #pragma unroll
        for (int c = 0; c < 2; ++c) {            // A: 8 chunks over 4 waves
            const int ch = c * 4 + w;
            gld_lds16(Abp + (size_t)ch * 16 * K + k0, &Ahs[ch * 16][0]);
            if constexpr (SPLIT)
                gld_lds16(Alp + (size_t)ch * 16 * K + k0, &Als[ch * 16][0]);
        }
        #pragma unroll
        for (int c = 0; c < NWC / 4; ++c) {      // W: NWC chunks over 4 waves
            const int ch = c * 4 + w;
            gld_lds16(Wbp + (size_t)ch * 16 * K + k0, &Whs[ch * 16][0]);
            if constexpr (SPLIT)
                gld_lds16(Wlp + (size_t)ch * 16 * K + k0, &Wls[ch * 16][0]);
        }
        __syncthreads();   // vmcnt drain + barrier: tiles visible

        bf16x8 af[4], bfr[FN];
        #pragma unroll
        for (int i = 0; i < 4; ++i) af[i] = *(const bf16x8*)&Ahs[wr * 64 + 16 * i + lr][lh * 8];
        #pragma unroll
        for (int j = 0; j < FN; ++j) bfr[j] = *(const bf16x8*)&Whs[wc * WN + 16 * j + lr][lh * 8];
        #pragma unroll
        for (int i = 0; i < 4; ++i)
            #pragma unroll
            for (int j = 0; j < FN; ++j)
                acc[i][j] = __builtin_amdgcn_mfma_f32_16x16x32_bf16(af[i], bfr[j], acc[i][j], 0, 0, 0);
        if constexpr (SPLIT) {
            bf16x8 al8[4], wl8[FN];
            #pragma unroll
            for (int i = 0; i < 4; ++i) al8[i] = *(const bf16x8*)&Als[wr * 64 + 16 * i + lr][lh * 8];
            #pragma unroll
            for (int j = 0; j < FN; ++j) wl8[j] = *(const bf16x8*)&Wls[wc * WN + 16 * j + lr][lh * 8];
            #pragma unroll
            for (int i = 0; i < 4; ++i)
                #pragma unroll
                for (int j = 0; j < FN; ++j) {
                    acc[i][j] = __builtin_amdgcn_mfma_f32_16x16x32_bf16(al8[i], bfr[j], acc[i][j], 0, 0, 0);
                    acc[i][j] = __builtin_amdgcn_mfma_f32_16x16x32_bf16(af[i], wl8[j], acc[i][j], 0, 0, 0);
                }
        }
        __syncthreads();   // all reads done before next stage overwrites
    }

    float bv[FN];
    #pragma unroll
    for (int j = 0; j < FN; ++j) bv[j] = bias[n0 + wc * WN + 16 * j + lr];
    #pragma unroll
    for (int i = 0; i < 4; ++i) {
        const int mb = m0 + wr * 64 + 16 * i + 4 * lh;
        #pragma unroll
        for (int j = 0; j < FN; ++j) {
            const int n = n0 + wc * WN + 16 * j + lr;
            #pragma unroll
            for (int r = 0; r < 4; ++r) {
                const float v = acc[i][j][r] + bv[j];
                if constexpr (OUTBF) ((__bf16*)Cout)[(size_t)(mb + r) * N + n] = (__bf16)v;
                else                 ((float*)Cout)[(size_t)(mb + r) * N + n] = v;
            }
        }
    }
}

// ---------------- wave helpers ----------------
__device__ inline float wave64_sum(float v) {
    #pragma unroll
    for (int off = 32; off >= 1; off >>= 1) v += __shfl_xor(v, off);
    return v;
}

// ---------------- q: LayerNorm + rotary -> bf16 [bgh][s][d] ----------------
__global__ __launch_bounds__(256)
void q_transform(const __bf16* __restrict__ q_lin, const float* __restrict__ gam,
                 const float* __restrict__ bet, const int* __restrict__ t_id,
                 __bf16* __restrict__ q_n) {
    const int row  = blockIdx.x * 4 + (threadIdx.x >> 6);
    const int lane = threadIdx.x & 63;
    const int s    = row & (S - 1);
    const int bgh  = row >> 10;
    const int b    = bgh >> 4;
    const int gh   = bgh & 15;
    float x = (float)q_lin[(size_t)(b * S + s) * DIMM + gh * HD + lane];
    const float m = wave64_sum(x) * (1.0f / 64.0f);
    const float d = x - m;
    const float v = wave64_sum(d * d) * (1.0f / 64.0f);
    float y = d * rsqrtf(v + LNEPS) * gam[lane] + bet[lane];
    const float partner = __shfl_xor(y, 1);
    if (lane < PW) {
        const int i = lane >> 1;
        const float theta = expf(-0.57564627324851f * (float)i);
        const float ang = (float)t_id[b * S + s] * theta;
        const float cs = cosf(ang), sn = sinf(ang);
        y = cs * y + sn * ((lane & 1) ? partner : -partner);
    }
    q_n[(size_t)row * HD + lane] = (__bf16)y;
}

// ---------------- k: LayerNorm + rotary -> bf16 [bg][s][d] ----------------
__global__ __launch_bounds__(256)
void k_transform(const __bf16* __restrict__ kv_lin, const float* __restrict__ gam,
                 const float* __restrict__ bet, const int* __restrict__ t_id,
                 __bf16* __restrict__ k_n) {
    const int row  = blockIdx.x * 4 + (threadIdx.x >> 6);
    const int lane = threadIdx.x & 63;
    const int s    = row & (S - 1);
    const int bg   = row >> 10;
    const int b    = bg >> 2;
    const int g    = bg & 3;
    float x = (float)kv_lin[(size_t)(b * S + s) * 512 + g * HD + lane];
    const float m = wave64_sum(x) * (1.0f / 64.0f);
    const float d = x - m;
    const float v = wave64_sum(d * d) * (1.0f / 64.0f);
    float y = d * rsqrtf(v + LNEPS) * gam[lane] + bet[lane];
    const float partner = __shfl_xor(y, 1);
    if (lane < PW) {
        const int i = lane >> 1;
        const float theta = expf(-0.57564627324851f * (float)i);
        const float ang = (float)t_id[b * S + s] * theta;
        const float cs = cosf(ang), sn = sinf(ang);
        y = cs * y + sn * ((lane & 1) ? partner : -partner);
    }
    k_n[(size_t)row * HD + lane] = (__bf16)y;
}

// ---------------- V transpose: bf16 kv_lin[b][s][256+g*64+d] -> bf16 [bg][d][s] ----
__global__ __launch_bounds__(256)
void v_transpose(const __bf16* __restrict__ kv_lin, __bf16* __restrict__ vt) {
    __shared__ float T[64][65];
    const int bg = blockIdx.x >> 4;
    const int s0 = (blockIdx.x & 15) * 64;
    const int b = bg >> 2, g = bg & 3;
    const int tx = threadIdx.x & 63, ty = threadIdx.x >> 6;
    const __bf16* src = kv_lin + ((size_t)(b * S) + s0) * 512 + 256 + g * HD;
    #pragma unroll
    for (int i = 0; i < 16; ++i) {
        const int sp = ty + 4 * i;
        T[sp][tx] = (float)src[(size_t)sp * 512 + tx];
    }
    __syncthreads();
    __bf16* dst = vt + (size_t)bg * HD * S + s0;
    #pragma unroll
    for (int i = 0; i < 16; ++i) {
        const int d = ty + 4 * i;
        dst[(size_t)d * S + tx] = (__bf16)T[tx][d];
    }
}

// ---------------- flash attention, bf16 MFMA; epilogue emits hi/lo bf16 ----------------
__global__ __launch_bounds__(256)
void flash_mfma(const __bf16* __restrict__ q_n, const __bf16* __restrict__ k_n,
                const __bf16* __restrict__ vt, const float* __restrict__ var_emb,
                const int* __restrict__ qvar, const int* __restrict__ kvar,
                __bf16* __restrict__ attn_h, __bf16* __restrict__ attn_l) {
    __shared__ float Ss[4][64][20];

    const int tid = threadIdx.x;
    const int w = tid >> 6, l = tid & 63;
    const int lr = l & 15, lh = l >> 4;
    const int qb = blockIdx.x & 15;
    const int bgh = blockIdx.x >> 4;
    const int b = bgh >> 4, gh = bgh & 15;
    const int bg = bgh >> 2;

    const int q0 = qb * 64 + w * 16;

    const __bf16* qbase = q_n + ((size_t)bgh * S + q0 + lr) * HD + 8 * lh;
    const bf16x8 qa0 = *(const bf16x8*)(qbase);
    const bf16x8 qa1 = *(const bf16x8*)(qbase + 32);

    const int   qv = qvar[b * S + q0 + lr];
    const float w0 = var_emb[gh];
    const float w1 = var_emb[16 + gh];

    const __bf16* kbase = k_n + (size_t)bg * S * HD;
    const __bf16* vbase = vt + (size_t)bg * HD * S;
    const int* kvb = kvar + b * S;

    f32x4 O[4];
    #pragma unroll
    for (int t = 0; t < 4; ++t) O[t] = (f32x4){0.f, 0.f, 0.f, 0.f};
    float mrun = -1e30f, lrun = 0.0f;

    for (int k0 = 0; k0 < S; k0 += 64) {
        f32x4 st[4];
        #pragma unroll
        for (int t = 0; t < 4; ++t) {
            const __bf16* kp = kbase + (size_t)(k0 + 16 * t + lr) * HD + 8 * lh;
            const bf16x8 kb0 = *(const bf16x8*)(kp);
            const bf16x8 kb1 = *(const bf16x8*)(kp + 32);
            f32x4 acc = (f32x4){0.f, 0.f, 0.f, 0.f};
            acc = __builtin_amdgcn_mfma_f32_16x16x32_bf16(qa0, kb0, acc, 0, 0, 0);
            acc = __builtin_amdgcn_mfma_f32_16x16x32_bf16(qa1, kb1, acc, 0, 0, 0);
            st[t] = acc;
        }
        #pragma unroll
        for (int t = 0; t < 4; ++t)
            *(f32x4*)&Ss[w][16 * t + lr][4 * lh] = st[t];

        float sv[2][8];
        float tmax = -1e30f;
        #pragma unroll
        for (int c = 0; c < 2; ++c) {
            int kvi[8];
            *(int4*)(&kvi[0]) = *(const int4*)(kvb + k0 + 32 * c + 8 * lh);
            *(int4*)(&kvi[4]) = *(const int4*)(kvb + k0 + 32 * c + 8 * lh + 4);
            #pragma unroll
            for (int e = 0; e < 8; ++e) {
                float sc = Ss[w][32 * c + 8 * lh + e][lr];
                sc = sc * SCALE + ((qv == kvi[e]) ? w1 : w0);
                sv[c][e] = sc;
                tmax = fmaxf(tmax, sc);
            }
        }
        tmax = fmaxf(tmax, __shfl_xor(tmax, 16));
        tmax = fmaxf(tmax, __shfl_xor(tmax, 32));
        const float mnew  = fmaxf(mrun, tmax);
        const float alpha = __expf(mrun - mnew);
        float psum = 0.0f;
        bf16x8 pa0, pa1;
        #pragma unroll
        for (int e = 0; e < 8; ++e) {
            const float p0 = __expf(sv[0][e] - mnew);
            const float p1 = __expf(sv[1][e] - mnew);
            psum += p0 + p1;
            pa0[e] = (__bf16)p0;
            pa1[e] = (__bf16)p1;
        }
        psum += __shfl_xor(psum, 16);
        psum += __shfl_xor(psum, 32);
        lrun = lrun * alpha + psum;
        mrun = mnew;

        const float a0 = __shfl(alpha, 4 * lh + 0);
        const float a1 = __shfl(alpha, 4 * lh + 1);
        const float a2 = __shfl(alpha, 4 * lh + 2);
        const float a3 = __shfl(alpha, 4 * lh + 3);
        #pragma unroll
        for (int t = 0; t < 4; ++t) {
            O[t][0] *= a0; O[t][1] *= a1; O[t][2] *= a2; O[t][3] *= a3;
        }

        #pragma unroll
        for (int t = 0; t < 4; ++t) {
            const __bf16* vp = vbase + (size_t)(16 * t + lr) * S + k0 + 8 * lh;
            const bf16x8 vb0 = *(const bf16x8*)(vp);
            const bf16x8 vb1 = *(const bf16x8*)(vp + 32);
            O[t] = __builtin_amdgcn_mfma_f32_16x16x32_bf16(pa0, vb0, O[t], 0, 0, 0);
            O[t] = __builtin_amdgcn_mfma_f32_16x16x32_bf16(pa1, vb1, O[t], 0, 0, 0);
        }
    }

    const float l0 = 1.0f / __shfl(lrun, 4 * lh + 0);
    const float l1 = 1.0f / __shfl(lrun, 4 * lh + 1);
    const float l2 = 1.0f / __shfl(lrun, 4 * lh + 2);
    const float l3 = 1.0f / __shfl(lrun, 4 * lh + 3);
    #pragma unroll
    for (int t = 0; t < 4; ++t) {
        const size_t base = ((size_t)(b * S + q0 + 4 * lh)) * DIMM + gh * HD + 16 * t + lr;
        const float lv[4] = {l0, l1, l2, l3};
        #pragma unroll
        for (int r = 0; r < 4; ++r) {
            const float v = O[t][r] * lv[r];
            const __bf16 h = (__bf16)v;
            attn_h[base + (size_t)r * DIMM] = h;
            attn_l[base + (size_t)r * DIMM] = (__bf16)(v - (float)h);
        }
    }
}

extern "C" void kernel_launch(void* const* d_in, const int* in_sizes, int n_in,
                              void* d_out, int out_size, void* d_ws, size_t ws_size,
                              hipStream_t stream) {
    const float* x     = (const float*)d_in[0];
    const float* kv    = (const float*)d_in[1];
    const float* q_w   = (const float*)d_in[2];
    const float* q_b   = (const float*)d_in[3];
    const float* k_w   = (const float*)d_in[4];
    const float* k_b   = (const float*)d_in[5];
    const float* v_w   = (const float*)d_in[6];
    const float* v_b   = (const float*)d_in[7];
    const float* o_w   = (const float*)d_in[8];
    const float* o_b   = (const float*)d_in[9];
    const float* qn_g  = (const float*)d_in[10];
    const float* qn_b  = (const float*)d_in[11];
    const float* kn_g  = (const float*)d_in[12];
    const float* kn_b  = (const float*)d_in[13];
    const float* vemb  = (const float*)d_in[14];
    const int*   qvar  = (const int*)d_in[15];
    const int*   kvar  = (const int*)d_in[16];
    const int*   qtime = (const int*)d_in[17];
    const int*   ktime = (const int*)d_in[18];
    float* out = (float*)d_out;
    char*  W   = (char*)d_ws;

    const size_t MB = 1u << 20;
    // phase-overlaid layout, 44 MB total
    __bf16* xh     = (__bf16*)(W);                 // 0-8   -> attn_h after G1
    __bf16* kvh    = (__bf16*)(W + 8 * MB);        // 8-16  -> attn_l after G2
    __bf16* q_lin  = (__bf16*)(W + 16 * MB);       // 16-24
    __bf16* kv_lin = (__bf16*)(W + 24 * MB);       // 24-28
    __bf16* q_nb   = (__bf16*)(W + 28 * MB);       // 28-36 (overlays qwh/kvwh/kvb, dead by then)
    __bf16* qwh    = (__bf16*)(W + 28 * MB);       //  2 MB
    __bf16* kvwh   = (__bf16*)(W + 30 * MB);       //  1 MB
    float*  kvb    = (float*)(W + 31 * MB);        //  2 KB
    __bf16* k_nb   = (__bf16*)(W + 36 * MB);       // 36-38
    __bf16* vtb    = (__bf16*)(W + 38 * MB);       // 38-40
    __bf16* owh    = (__bf16*)(W + 40 * MB);       // 40-42
    __bf16* owl    = (__bf16*)(W + 42 * MB);       // 42-44
    __bf16* attn_h = xh;
    __bf16* attn_l = kvh;

    dim3 blk(256);

    // conversions
    cvt_bf16<<<2048, blk, 0, stream>>>(x,   xh,   nullptr, 524288);
    cvt_bf16<<<2048, blk, 0, stream>>>(kv,  kvh,  nullptr, 524288);
    cvt_bf16<<<512,  blk, 0, stream>>>(q_w, qwh,  nullptr, 131072);
    cvt_bf16<<<128,  blk, 0, stream>>>(k_w, kvwh,              nullptr, 32768);
    cvt_bf16<<<128,  blk, 0, stream>>>(v_w, kvwh + 256 * 1024, nullptr, 32768);
    cvt_bf16<<<512,  blk, 0, stream>>>(o_w, owh,  owl, 131072);
    concat_bias<<<1, blk, 0, stream>>>(k_b, v_b, kvb);

    // projections (MFMA)
    gemm_mfma<128, false, true><<<dim3(8, 32), blk, 0, stream>>>(
        xh, nullptr, qwh, nullptr, q_b, (void*)q_lin, 1024, 1024);
    gemm_mfma<64, false, true><<<dim3(8, 32), blk, 0, stream>>>(
        kvh, nullptr, kvwh, nullptr, kvb, (void*)kv_lin, 512, 1024);

    // transforms
    q_transform<<<(4 * G * HPG * S) / 4, blk, 0, stream>>>(q_lin, qn_g, qn_b, qtime, q_nb);
    k_transform<<<(4 * G * S) / 4,       blk, 0, stream>>>(kv_lin, kn_g, kn_b, ktime, k_nb);
    v_transpose<<<16 * 16,               blk, 0, stream>>>(kv_lin, vtb);

    // attention
    flash_mfma<<<4 * G * HPG * (S / 64), blk, 0, stream>>>(
        q_nb, k_nb, vtb, vemb, qvar, kvar, attn_h, attn_l);

    // output projection (split, f32-accurate)
    gemm_mfma<128, true, false><<<dim3(8, 32), blk, 0, stream>>>(
        attn_h, attn_l, owh, owl, o_b, (void*)out, 1024, 1024);
}

// Round 4
// 267.548 us; speedup vs baseline: 3.2534x; 1.0213x over previous
//
#include <hip/hip_runtime.h>
#include <math.h>

#define S 1024
#define DIMM 1024
#define G 4
#define HPG 4
#define HD 64
#define PW 32
#define SCALE 0.125f
#define LNEPS 1e-5f

typedef __bf16 bf16x8 __attribute__((ext_vector_type(8)));
typedef float  f32x4  __attribute__((ext_vector_type(4)));

// ---------------- fused f32->bf16 conversions + bias concat ----------------
// segments (groups of 8 elems): x 524288 | kv 524288 | q_w 131072 | k_w 32768
//                               | v_w 32768 | o_w 131072 (hi+lo)
__global__ __launch_bounds__(256)
void cvt_all(const float* __restrict__ x, const float* __restrict__ kv,
             const float* __restrict__ qw, const float* __restrict__ kw,
             const float* __restrict__ vw, const float* __restrict__ ow,
             const float* __restrict__ kb, const float* __restrict__ vb_,
             __bf16* __restrict__ xh, __bf16* __restrict__ kvh,
             __bf16* __restrict__ qwh, __bf16* __restrict__ kvwh,
             __bf16* __restrict__ owh, __bf16* __restrict__ owl,
             float* __restrict__ kvbias) {
    if (blockIdx.x == 5376) {
        kvbias[threadIdx.x]       = kb[threadIdx.x];
        kvbias[256 + threadIdx.x] = vb_[threadIdx.x];
        return;
    }
    long j = (long)blockIdx.x * 256 + threadIdx.x;
    const float* src; __bf16* dh; __bf16* dl = nullptr;
    if (j < 524288)            { src = x;  dh = xh; }
    else if ((j -= 524288) < 524288) { src = kv; dh = kvh; }
    else if ((j -= 524288) < 131072) { src = qw; dh = qwh; }
    else if ((j -= 131072) < 32768)  { src = kw; dh = kvwh; }
    else if ((j -= 32768) < 32768)   { src = vw; dh = kvwh + 262144; }
    else { j -= 32768; src = ow; dh = owh; dl = owl; }
    const float4 a = *(const float4*)(src + j * 8);
    const float4 b = *(const float4*)(src + j * 8 + 4);
    const float v[8] = {a.x, a.y, a.z, a.w, b.x, b.y, b.z, b.w};
    bf16x8 H;
    #pragma unroll
    for (int e = 0; e < 8; ++e) H[e] = (__bf16)v[e];
    *(bf16x8*)(dh + j * 8) = H;
    if (dl != nullptr) {
        bf16x8 L;
        #pragma unroll
        for (int e = 0; e < 8; ++e) L[e] = (__bf16)(v[e] - (float)H[e]);
        *(bf16x8*)(dl + j * 8) = L;
    }
}

// ---------------- bf16 MFMA GEMM (m97 structure) ----------------
__device__ __forceinline__ void gld_lds16(const __bf16* g, __bf16* lds) {
    __builtin_amdgcn_global_load_lds(
        (const __attribute__((address_space(1))) void*)g,
        (__attribute__((address_space(3))) void*)lds, 16, 0, 0);
}

template<int NB, bool SPLIT, bool OUTBF>
__global__ __launch_bounds__(256)
void gemm_mfma(const __bf16* __restrict__ Ah, const __bf16* __restrict__ Al,
               const __bf16* __restrict__ Wh, const __bf16* __restrict__ Wl,
               const float* __restrict__ bias, void* __restrict__ Cout,
               const int N, const int K) {
    constexpr int WN  = NB / 2;
    constexpr int FN  = WN / 16;
    constexpr int NWC = NB / 16;
    __shared__ __bf16 Ahs[128][32];
    __shared__ __bf16 Whs[NB][32];
    __shared__ __bf16 Als[SPLIT ? 128 : 1][32];
    __shared__ __bf16 Wls[SPLIT ? NB : 1][32];

    const int tid = threadIdx.x;
    const int w = tid >> 6, l = tid & 63;
    const int lr = l & 15, lh = l >> 4;
    const int wr = w >> 1, wc = w & 1;
    const int m0 = blockIdx.y * 128, n0 = blockIdx.x * NB;
    const int srow = l >> 2, scol = (l & 3) * 8;

    f32x4 acc[4][FN];
    #pragma unroll
    for (int i = 0; i < 4; ++i)
        #pragma unroll
        for (int j = 0; j < FN; ++j) acc[i][j] = (f32x4){0.f, 0.f, 0.f, 0.f};

    const __bf16* Abp = Ah + (size_t)(m0 + srow) * K + scol;
    const __bf16* Wbp = Wh + (size_t)(n0 + srow) * K + scol;
    const __bf16* Alp = SPLIT ? (Al + (size_t)(m0 + srow) * K + scol) : nullptr;
    const __bf16* Wlp = SPLIT ? (Wl + (size_t)(n0 + srow) * K + scol) : nullptr;

    for (int k0 = 0; k0 < K; k0 += 32) {
        #pragma unroll
        for (int c = 0; c < 2; ++c) {
            const int ch = c * 4 + w;
            gld_lds16(Abp + (size_t)ch * 16 * K + k0, &Ahs[ch * 16][0]);
            if constexpr (SPLIT)
                gld_lds16(Alp + (size_t)ch * 16 * K + k0, &Als[ch * 16][0]);
        }
        #pragma unroll
        for (int c = 0; c < NWC / 4; ++c) {
            const int ch = c * 4 + w;
            gld_lds16(Wbp + (size_t)ch * 16 * K + k0, &Whs[ch * 16][0]);
            if constexpr (SPLIT)
                gld_lds16(Wlp + (size_t)ch * 16 * K + k0, &Wls[ch * 16][0]);
        }
        __syncthreads();

        bf16x8 af[4], bfr[FN];
        #pragma unroll
        for (int i = 0; i < 4; ++i) af[i] = *(const bf16x8*)&Ahs[wr * 64 + 16 * i + lr][lh * 8];
        #pragma unroll
        for (int j = 0; j < FN; ++j) bfr[j] = *(const bf16x8*)&Whs[wc * WN + 16 * j + lr][lh * 8];
        #pragma unroll
        for (int i = 0; i < 4; ++i)
            #pragma unroll
            for (int j = 0; j < FN; ++j)
                acc[i][j] = __builtin_amdgcn_mfma_f32_16x16x32_bf16(af[i], bfr[j], acc[i][j], 0, 0, 0);
        if constexpr (SPLIT) {
            bf16x8 al8[4], wl8[FN];
            #pragma unroll
            for (int i = 0; i < 4; ++i) al8[i] = *(const bf16x8*)&Als[wr * 64 + 16 * i + lr][lh * 8];
            #pragma unroll
            for (int j = 0; j < FN; ++j) wl8[j] = *(const bf16x8*)&Wls[wc * WN + 16 * j + lr][lh * 8];
            #pragma unroll
            for (int i = 0; i < 4; ++i)
                #pragma unroll
                for (int j = 0; j < FN; ++j) {
                    acc[i][j] = __builtin_amdgcn_mfma_f32_16x16x32_bf16(al8[i], bfr[j], acc[i][j], 0, 0, 0);
                    acc[i][j] = __builtin_amdgcn_mfma_f32_16x16x32_bf16(af[i], wl8[j], acc[i][j], 0, 0, 0);
                }
        }
        __syncthreads();
    }

    float bv[FN];
    #pragma unroll
    for (int j = 0; j < FN; ++j) bv[j] = bias[n0 + wc * WN + 16 * j + lr];
    #pragma unroll
    for (int i = 0; i < 4; ++i) {
        const int mb = m0 + wr * 64 + 16 * i + 4 * lh;
        #pragma unroll
        for (int j = 0; j < FN; ++j) {
            const int n = n0 + wc * WN + 16 * j + lr;
            #pragma unroll
            for (int r = 0; r < 4; ++r) {
                const float v = acc[i][j][r] + bv[j];
                if constexpr (OUTBF) ((__bf16*)Cout)[(size_t)(mb + r) * N + n] = (__bf16)v;
                else                 ((float*)Cout)[(size_t)(mb + r) * N + n] = v;
            }
        }
    }
}

// ---------------- wave helpers ----------------
__device__ inline float wave64_sum(float v) {
    #pragma unroll
    for (int off = 32; off >= 1; off >>= 1) v += __shfl_xor(v, off);
    return v;
}

// ---------------- q: LayerNorm + rotary -> bf16 [bgh][s][d] ----------------
__global__ __launch_bounds__(256)
void q_transform(const __bf16* __restrict__ q_lin, const float* __restrict__ gam,
                 const float* __restrict__ bet, const int* __restrict__ t_id,
                 __bf16* __restrict__ q_n) {
    const int row  = blockIdx.x * 4 + (threadIdx.x >> 6);
    const int lane = threadIdx.x & 63;
    const int s    = row & (S - 1);
    const int bgh  = row >> 10;
    const int b    = bgh >> 4;
    const int gh   = bgh & 15;
    float x = (float)q_lin[(size_t)(b * S + s) * DIMM + gh * HD + lane];
    const float m = wave64_sum(x) * (1.0f / 64.0f);
    const float d = x - m;
    const float v = wave64_sum(d * d) * (1.0f / 64.0f);
    float y = d * rsqrtf(v + LNEPS) * gam[lane] + bet[lane];
    const float partner = __shfl_xor(y, 1);
    if (lane < PW) {
        const int i = lane >> 1;
        const float theta = expf(-0.57564627324851f * (float)i);
        const float ang = (float)t_id[b * S + s] * theta;
        const float cs = cosf(ang), sn = sinf(ang);
        y = cs * y + sn * ((lane & 1) ? partner : -partner);
    }
    q_n[(size_t)row * HD + lane] = (__bf16)y;
}

// ---------------- k: LayerNorm + rotary -> bf16 [bg][s][d] ----------------
__global__ __launch_bounds__(256)
void k_transform(const __bf16* __restrict__ kv_lin, const float* __restrict__ gam,
                 const float* __restrict__ bet, const int* __restrict__ t_id,
                 __bf16* __restrict__ k_n) {
    const int row  = blockIdx.x * 4 + (threadIdx.x >> 6);
    const int lane = threadIdx.x & 63;
    const int s    = row & (S - 1);
    const int bg   = row >> 10;
    const int b    = bg >> 2;
    const int g    = bg & 3;
    float x = (float)kv_lin[(size_t)(b * S + s) * 512 + g * HD + lane];
    const float m = wave64_sum(x) * (1.0f / 64.0f);
    const float d = x - m;
    const float v = wave64_sum(d * d) * (1.0f / 64.0f);
    float y = d * rsqrtf(v + LNEPS) * gam[lane] + bet[lane];
    const float partner = __shfl_xor(y, 1);
    if (lane < PW) {
        const int i = lane >> 1;
        const float theta = expf(-0.57564627324851f * (float)i);
        const float ang = (float)t_id[b * S + s] * theta;
        const float cs = cosf(ang), sn = sinf(ang);
        y = cs * y + sn * ((lane & 1) ? partner : -partner);
    }
    k_n[(size_t)row * HD + lane] = (__bf16)y;
}

// ---------------- V transpose: bf16 kv_lin[b][s][256+g*64+d] -> bf16 [bg][d][s] ----
__global__ __launch_bounds__(256)
void v_transpose(const __bf16* __restrict__ kv_lin, __bf16* __restrict__ vt) {
    __shared__ float T[64][65];
    const int bg = blockIdx.x >> 4;
    const int s0 = (blockIdx.x & 15) * 64;
    const int b = bg >> 2, g = bg & 3;
    const int tx = threadIdx.x & 63, ty = threadIdx.x >> 6;
    const __bf16* src = kv_lin + ((size_t)(b * S) + s0) * 512 + 256 + g * HD;
    #pragma unroll
    for (int i = 0; i < 16; ++i) {
        const int sp = ty + 4 * i;
        T[sp][tx] = (float)src[(size_t)sp * 512 + tx];
    }
    __syncthreads();
    __bf16* dst = vt + (size_t)bg * HD * S + s0;
    #pragma unroll
    for (int i = 0; i < 16; ++i) {
        const int d = ty + 4 * i;
        dst[(size_t)d * S + tx] = (__bf16)T[tx][d];
    }
}

// ---------------- flash attention v2: swapped QK^T, in-register softmax ------
// 4 waves/block, wave owns 16 q-rows; no LDS, no barriers; K prefetch 1 tile.
__global__ __launch_bounds__(256)
void flash_mfma(const __bf16* __restrict__ q_n, const __bf16* __restrict__ k_n,
                const __bf16* __restrict__ vt, const float* __restrict__ var_emb,
                const int* __restrict__ qvar, const int* __restrict__ kvar,
                __bf16* __restrict__ attn_h, __bf16* __restrict__ attn_l) {
    const int tid = threadIdx.x;
    const int w = tid >> 6, l = tid & 63;
    const int lr = l & 15, lh = l >> 4;
    const int qb = blockIdx.x & 15;
    const int bgh = blockIdx.x >> 4;
    const int b = bgh >> 4, gh = bgh & 15;
    const int bg = bgh >> 2;
    const int q0 = qb * 64 + w * 16;

    // Q fragment (B-operand): lane holds Q[q=lr][d=8*lh+e]
    const __bf16* qbase = q_n + ((size_t)bgh * S + q0 + lr) * HD + 8 * lh;
    const bf16x8 qa0 = *(const bf16x8*)(qbase);
    const bf16x8 qa1 = *(const bf16x8*)(qbase + 32);

    constexpr float L2E = 1.4426950408889634f;
    const int   qv  = qvar[b * S + q0 + lr];
    const float w0l = var_emb[gh] * L2E;
    const float w1l = var_emb[16 + gh] * L2E;
    const float sc2 = SCALE * L2E;

    const __bf16* kbase = k_n + (size_t)bg * S * HD;
    const __bf16* vbase = vt + (size_t)bg * HD * S;
    const int* kvb = kvar + b * S;

    f32x4 O[4];
    #pragma unroll
    for (int t = 0; t < 4; ++t) O[t] = (f32x4){0.f, 0.f, 0.f, 0.f};
    float mrun = -3.0e38f, lrun = 0.0f;

    // preload K tile 0 (A-operand: lane holds K[k=16t+lr][d=8*lh+e])
    bf16x8 kb[4][2];
    #pragma unroll
    for (int t = 0; t < 4; ++t) {
        const __bf16* kp = kbase + (size_t)(16 * t + lr) * HD + 8 * lh;
        kb[t][0] = *(const bf16x8*)(kp);
        kb[t][1] = *(const bf16x8*)(kp + 32);
    }

    for (int k0 = 0; k0 < S; k0 += 64) {
        // V + kvar loads for current tile (consumed after softmax)
        bf16x8 vb[4][2];
        #pragma unroll
        for (int t = 0; t < 4; ++t) {
            const __bf16* vp = vbase + (size_t)(16 * t + lr) * S + k0 + 8 * lh;
            vb[t][0] = *(const bf16x8*)(vp);
            vb[t][1] = *(const bf16x8*)(vp + 32);
        }
        int4 kvi[4];
        #pragma unroll
        for (int t = 0; t < 4; ++t)
            kvi[t] = *(const int4*)(kvb + k0 + 16 * t + 4 * lh);

        // swapped QK^T: lane holds S[k=16t+4*lh+r][q=lr]
        f32x4 st[4];
        #pragma unroll
        for (int t = 0; t < 4; ++t) {
            f32x4 acc = (f32x4){0.f, 0.f, 0.f, 0.f};
            acc = __builtin_amdgcn_mfma_f32_16x16x32_bf16(kb[t][0], qa0, acc, 0, 0, 0);
            acc = __builtin_amdgcn_mfma_f32_16x16x32_bf16(kb[t][1], qa1, acc, 0, 0, 0);
            st[t] = acc;
        }

        // prefetch next K tile (hidden under softmax + PV)
        const int kn = (k0 + 64 < S) ? k0 + 64 : 0;
        #pragma unroll
        for (int t = 0; t < 4; ++t) {
            const __bf16* kp = kbase + (size_t)(kn + 16 * t + lr) * HD + 8 * lh;
            kb[t][0] = *(const bf16x8*)(kp);
            kb[t][1] = *(const bf16x8*)(kp + 32);
        }

        // bias + scale (log2 domain) + tile max
        float tmax = -3.0e38f;
        #pragma unroll
        for (int t = 0; t < 4; ++t) {
            st[t][0] = fmaf(st[t][0], sc2, (qv == kvi[t].x) ? w1l : w0l);
            st[t][1] = fmaf(st[t][1], sc2, (qv == kvi[t].y) ? w1l : w0l);
            st[t][2] = fmaf(st[t][2], sc2, (qv == kvi[t].z) ? w1l : w0l);
            st[t][3] = fmaf(st[t][3], sc2, (qv == kvi[t].w) ? w1l : w0l);
            tmax = fmaxf(tmax, fmaxf(fmaxf(st[t][0], st[t][1]), fmaxf(st[t][2], st[t][3])));
        }
        tmax = fmaxf(tmax, __shfl_xor(tmax, 16));
        tmax = fmaxf(tmax, __shfl_xor(tmax, 32));

        // defer-max (THR = 8 nats = 11.54 in log2)
        float mref = mrun;
        if (!__all(tmax - mrun <= 11.54f)) {
            const float mnew = fmaxf(mrun, tmax);
            const float alpha = exp2f(mrun - mnew);
            const float a0 = __shfl(alpha, 4 * lh + 0);
            const float a1 = __shfl(alpha, 4 * lh + 1);
            const float a2 = __shfl(alpha, 4 * lh + 2);
            const float a3 = __shfl(alpha, 4 * lh + 3);
            #pragma unroll
            for (int t = 0; t < 4; ++t) {
                O[t][0] *= a0; O[t][1] *= a1; O[t][2] *= a2; O[t][3] *= a3;
            }
            lrun *= alpha;
            mrun = mnew; mref = mnew;
        }

        // P = exp2(st - mref); pack pairs to bf16 u32s
        float psum = 0.0f;
        unsigned int u[4][2];
        #pragma unroll
        for (int t = 0; t < 4; ++t) {
            const float p0 = exp2f(st[t][0] - mref);
            const float p1 = exp2f(st[t][1] - mref);
            const float p2 = exp2f(st[t][2] - mref);
            const float p3 = exp2f(st[t][3] - mref);
            psum += (p0 + p1) + (p2 + p3);
            asm("v_cvt_pk_bf16_f32 %0, %1, %2" : "=v"(u[t][0]) : "v"(p0), "v"(p1));
            asm("v_cvt_pk_bf16_f32 %0, %1, %2" : "=v"(u[t][1]) : "v"(p2), "v"(p3));
        }
        psum += __shfl_xor(psum, 16);
        psum += __shfl_xor(psum, 32);
        lrun += psum;

        // gather A-fragments: pa0 = P[q=lr][k=8lh..8lh+7], pa1 = +32
        const int sA = ((2 * lh) & 3) * 16 + lr;
        const int sB = sA + 16;
        const bool hi = (lh >= 2);
        unsigned int g00 = __shfl(u[0][0], sA), g10 = __shfl(u[1][0], sA);
        unsigned int g01 = __shfl(u[0][1], sA), g11 = __shfl(u[1][1], sA);
        unsigned int g02 = __shfl(u[0][0], sB), g12 = __shfl(u[1][0], sB);
        unsigned int g03 = __shfl(u[0][1], sB), g13 = __shfl(u[1][1], sB);
        uint4 P0 = make_uint4(hi ? g10 : g00, hi ? g11 : g01,
                              hi ? g12 : g02, hi ? g13 : g03);
        unsigned int g20 = __shfl(u[2][0], sA), g30 = __shfl(u[3][0], sA);
        unsigned int g21 = __shfl(u[2][1], sA), g31 = __shfl(u[3][1], sA);
        unsigned int g22 = __shfl(u[2][0], sB), g32 = __shfl(u[3][0], sB);
        unsigned int g23 = __shfl(u[2][1], sB), g33 = __shfl(u[3][1], sB);
        uint4 P1 = make_uint4(hi ? g30 : g20, hi ? g31 : g21,
                              hi ? g32 : g22, hi ? g33 : g23);
        const bf16x8 pa0 = __builtin_bit_cast(bf16x8, P0);
        const bf16x8 pa1 = __builtin_bit_cast(bf16x8, P1);

        // PV: O[q=4lh+r][d=16t+lr]
        #pragma unroll
        for (int t = 0; t < 4; ++t) {
            O[t] = __builtin_amdgcn_mfma_f32_16x16x32_bf16(pa0, vb[t][0], O[t], 0, 0, 0);
            O[t] = __builtin_amdgcn_mfma_f32_16x16x32_bf16(pa1, vb[t][1], O[t], 0, 0, 0);
        }
    }

    const float l0 = 1.0f / __shfl(lrun, 4 * lh + 0);
    const float l1 = 1.0f / __shfl(lrun, 4 * lh + 1);
    const float l2 = 1.0f / __shfl(lrun, 4 * lh + 2);
    const float l3 = 1.0f / __shfl(lrun, 4 * lh + 3);
    const float lv[4] = {l0, l1, l2, l3};
    #pragma unroll
    for (int t = 0; t < 4; ++t) {
        const size_t base = ((size_t)(b * S + q0 + 4 * lh)) * DIMM + gh * HD + 16 * t + lr;
        #pragma unroll
        for (int r = 0; r < 4; ++r) {
            const float v = O[t][r] * lv[r];
            const __bf16 h = (__bf16)v;
            attn_h[base + (size_t)r * DIMM] = h;
            attn_l[base + (size_t)r * DIMM] = (__bf16)(v - (float)h);
        }
    }
}

extern "C" void kernel_launch(void* const* d_in, const int* in_sizes, int n_in,
                              void* d_out, int out_size, void* d_ws, size_t ws_size,
                              hipStream_t stream) {
    const float* x     = (const float*)d_in[0];
    const float* kv    = (const float*)d_in[1];
    const float* q_w   = (const float*)d_in[2];
    const float* q_b   = (const float*)d_in[3];
    const float* k_w   = (const float*)d_in[4];
    const float* k_b   = (const float*)d_in[5];
    const float* v_w   = (const float*)d_in[6];
    const float* v_b   = (const float*)d_in[7];
    const float* o_w   = (const float*)d_in[8];
    const float* o_b   = (const float*)d_in[9];
    const float* qn_g  = (const float*)d_in[10];
    const float* qn_b  = (const float*)d_in[11];
    const float* kn_g  = (const float*)d_in[12];
    const float* kn_b  = (const float*)d_in[13];
    const float* vemb  = (const float*)d_in[14];
    const int*   qvar  = (const int*)d_in[15];
    const int*   kvar  = (const int*)d_in[16];
    const int*   qtime = (const int*)d_in[17];
    const int*   ktime = (const int*)d_in[18];
    float* out = (float*)d_out;
    char*  W   = (char*)d_ws;

    const size_t MB = 1u << 20;
    __bf16* xh     = (__bf16*)(W);                 // 0-8   -> attn_h
    __bf16* kvh    = (__bf16*)(W + 8 * MB);        // 8-16  -> attn_l
    __bf16* q_lin  = (__bf16*)(W + 16 * MB);       // 16-24
    __bf16* kv_lin = (__bf16*)(W + 24 * MB);       // 24-28
    __bf16* q_nb   = (__bf16*)(W + 28 * MB);       // 28-36 (overlays qwh/kvwh/kvb)
    __bf16* qwh    = (__bf16*)(W + 28 * MB);
    __bf16* kvwh   = (__bf16*)(W + 30 * MB);
    float*  kvb    = (float*)(W + 31 * MB);
    __bf16* k_nb   = (__bf16*)(W + 36 * MB);       // 36-38
    __bf16* vtb    = (__bf16*)(W + 38 * MB);       // 38-40
    __bf16* owh    = (__bf16*)(W + 40 * MB);       // 40-42
    __bf16* owl    = (__bf16*)(W + 42 * MB);       // 42-44
    __bf16* attn_h = xh;
    __bf16* attn_l = kvh;

    dim3 blk(256);

    cvt_all<<<5377, blk, 0, stream>>>(x, kv, q_w, k_w, v_w, o_w, k_b, v_b,
                                      xh, kvh, qwh, kvwh, owh, owl, kvb);

    gemm_mfma<128, false, true><<<dim3(8, 32), blk, 0, stream>>>(
        xh, nullptr, qwh, nullptr, q_b, (void*)q_lin, 1024, 1024);
    gemm_mfma<64, false, true><<<dim3(8, 32), blk, 0, stream>>>(
        kvh, nullptr, kvwh, nullptr, kvb, (void*)kv_lin, 512, 1024);

    q_transform<<<(4 * G * HPG * S) / 4, blk, 0, stream>>>(q_lin, qn_g, qn_b, qtime, q_nb);
    k_transform<<<(4 * G * S) / 4,       blk, 0, stream>>>(kv_lin, kn_g, kn_b, ktime, k_nb);
    v_transpose<<<16 * 16,               blk, 0, stream>>>(kv_lin, vtb);

    flash_mfma<<<4 * G * HPG * (S / 64), blk, 0, stream>>>(
        q_nb, k_nb, vtb, vemb, qvar, kvar, attn_h, attn_l);

    gemm_mfma<128, true, false><<<dim3(8, 32), blk, 0, stream>>>(
        attn_h, attn_l, owh, owl, o_b, (void*)out, 1024, 1024);
}

// Round 5
// 213.841 us; speedup vs baseline: 4.0705x; 1.2512x over previous
//
#include <hip/hip_runtime.h>
#include <math.h>

#define S 1024
#define DIMM 1024
#define G 4
#define HPG 4
#define HD 64
#define PW 32
#define SCALE 0.125f
#define LNEPS 1e-5f

typedef __bf16 bf16x8 __attribute__((ext_vector_type(8)));
typedef float  f32x4  __attribute__((ext_vector_type(4)));
typedef float  f32x16 __attribute__((ext_vector_type(16)));

// ---------------- fused f32->bf16 conversions + bias concat ----------------
__global__ __launch_bounds__(256)
void cvt_all(const float* __restrict__ x, const float* __restrict__ kv,
             const float* __restrict__ qw, const float* __restrict__ kw,
             const float* __restrict__ vw, const float* __restrict__ ow,
             const float* __restrict__ kb, const float* __restrict__ vb_,
             __bf16* __restrict__ xh, __bf16* __restrict__ kvh,
             __bf16* __restrict__ qwh, __bf16* __restrict__ kvwh,
             __bf16* __restrict__ owh, __bf16* __restrict__ owl,
             float* __restrict__ kvbias) {
    if (blockIdx.x == 5376) {
        kvbias[threadIdx.x]       = kb[threadIdx.x];
        kvbias[256 + threadIdx.x] = vb_[threadIdx.x];
        return;
    }
    long j = (long)blockIdx.x * 256 + threadIdx.x;
    const float* src; __bf16* dh; __bf16* dl = nullptr;
    if (j < 524288)            { src = x;  dh = xh; }
    else if ((j -= 524288) < 524288) { src = kv; dh = kvh; }
    else if ((j -= 524288) < 131072) { src = qw; dh = qwh; }
    else if ((j -= 131072) < 32768)  { src = kw; dh = kvwh; }
    else if ((j -= 32768) < 32768)   { src = vw; dh = kvwh + 262144; }
    else { j -= 32768; src = ow; dh = owh; dl = owl; }
    const float4 a = *(const float4*)(src + j * 8);
    const float4 b = *(const float4*)(src + j * 8 + 4);
    const float v[8] = {a.x, a.y, a.z, a.w, b.x, b.y, b.z, b.w};
    bf16x8 H;
    #pragma unroll
    for (int e = 0; e < 8; ++e) H[e] = (__bf16)v[e];
    *(bf16x8*)(dh + j * 8) = H;
    if (dl != nullptr) {
        bf16x8 L;
        #pragma unroll
        for (int e = 0; e < 8; ++e) L[e] = (__bf16)(v[e] - (float)H[e]);
        *(bf16x8*)(dl + j * 8) = L;
    }
}

// ---------------- bf16 MFMA GEMM (m97 structure) ----------------
__device__ __forceinline__ void gld_lds16(const __bf16* g, __bf16* lds) {
    __builtin_amdgcn_global_load_lds(
        (const __attribute__((address_space(1))) void*)g,
        (__attribute__((address_space(3))) void*)lds, 16, 0, 0);
}

template<int NB, bool SPLIT, bool OUTBF>
__global__ __launch_bounds__(256)
void gemm_mfma(const __bf16* __restrict__ Ah, const __bf16* __restrict__ Al,
               const __bf16* __restrict__ Wh, const __bf16* __restrict__ Wl,
               const float* __restrict__ bias, void* __restrict__ Cout,
               const int N, const int K) {
    constexpr int WN  = NB / 2;
    constexpr int FN  = WN / 16;
    constexpr int NWC = NB / 16;
    __shared__ __bf16 Ahs[128][32];
    __shared__ __bf16 Whs[NB][32];
    __shared__ __bf16 Als[SPLIT ? 128 : 1][32];
    __shared__ __bf16 Wls[SPLIT ? NB : 1][32];

    const int tid = threadIdx.x;
    const int w = tid >> 6, l = tid & 63;
    const int lr = l & 15, lh = l >> 4;
    const int wr = w >> 1, wc = w & 1;
    const int m0 = blockIdx.y * 128, n0 = blockIdx.x * NB;
    const int srow = l >> 2, scol = (l & 3) * 8;

    f32x4 acc[4][FN];
    #pragma unroll
    for (int i = 0; i < 4; ++i)
        #pragma unroll
        for (int j = 0; j < FN; ++j) acc[i][j] = (f32x4){0.f, 0.f, 0.f, 0.f};

    const __bf16* Abp = Ah + (size_t)(m0 + srow) * K + scol;
    const __bf16* Wbp = Wh + (size_t)(n0 + srow) * K + scol;
    const __bf16* Alp = SPLIT ? (Al + (size_t)(m0 + srow) * K + scol) : nullptr;
    const __bf16* Wlp = SPLIT ? (Wl + (size_t)(n0 + srow) * K + scol) : nullptr;

    for (int k0 = 0; k0 < K; k0 += 32) {
        #pragma unroll
        for (int c = 0; c < 2; ++c) {
            const int ch = c * 4 + w;
            gld_lds16(Abp + (size_t)ch * 16 * K + k0, &Ahs[ch * 16][0]);
            if constexpr (SPLIT)
                gld_lds16(Alp + (size_t)ch * 16 * K + k0, &Als[ch * 16][0]);
        }
        #pragma unroll
        for (int c = 0; c < NWC / 4; ++c) {
            const int ch = c * 4 + w;
            gld_lds16(Wbp + (size_t)ch * 16 * K + k0, &Whs[ch * 16][0]);
            if constexpr (SPLIT)
                gld_lds16(Wlp + (size_t)ch * 16 * K + k0, &Wls[ch * 16][0]);
        }
        __syncthreads();

        bf16x8 af[4], bfr[FN];
        #pragma unroll
        for (int i = 0; i < 4; ++i) af[i] = *(const bf16x8*)&Ahs[wr * 64 + 16 * i + lr][lh * 8];
        #pragma unroll
        for (int j = 0; j < FN; ++j) bfr[j] = *(const bf16x8*)&Whs[wc * WN + 16 * j + lr][lh * 8];
        #pragma unroll
        for (int i = 0; i < 4; ++i)
            #pragma unroll
            for (int j = 0; j < FN; ++j)
                acc[i][j] = __builtin_amdgcn_mfma_f32_16x16x32_bf16(af[i], bfr[j], acc[i][j], 0, 0, 0);
        if constexpr (SPLIT) {
            bf16x8 al8[4], wl8[FN];
            #pragma unroll
            for (int i = 0; i < 4; ++i) al8[i] = *(const bf16x8*)&Als[wr * 64 + 16 * i + lr][lh * 8];
            #pragma unroll
            for (int j = 0; j < FN; ++j) wl8[j] = *(const bf16x8*)&Wls[wc * WN + 16 * j + lr][lh * 8];
            #pragma unroll
            for (int i = 0; i < 4; ++i)
                #pragma unroll
                for (int j = 0; j < FN; ++j) {
                    acc[i][j] = __builtin_amdgcn_mfma_f32_16x16x32_bf16(al8[i], bfr[j], acc[i][j], 0, 0, 0);
                    acc[i][j] = __builtin_amdgcn_mfma_f32_16x16x32_bf16(af[i], wl8[j], acc[i][j], 0, 0, 0);
                }
        }
        __syncthreads();
    }

    float bv[FN];
    #pragma unroll
    for (int j = 0; j < FN; ++j) bv[j] = bias[n0 + wc * WN + 16 * j + lr];
    #pragma unroll
    for (int i = 0; i < 4; ++i) {
        const int mb = m0 + wr * 64 + 16 * i + 4 * lh;
        #pragma unroll
        for (int j = 0; j < FN; ++j) {
            const int n = n0 + wc * WN + 16 * j + lr;
            #pragma unroll
            for (int r = 0; r < 4; ++r) {
                const float v = acc[i][j][r] + bv[j];
                if constexpr (OUTBF) ((__bf16*)Cout)[(size_t)(mb + r) * N + n] = (__bf16)v;
                else                 ((float*)Cout)[(size_t)(mb + r) * N + n] = v;
            }
        }
    }
}

// ---------------- wave helpers ----------------
__device__ inline float wave64_sum(float v) {
    #pragma unroll
    for (int off = 32; off >= 1; off >>= 1) v += __shfl_xor(v, off);
    return v;
}

// ---------------- q: LayerNorm + rotary -> bf16 [bgh][s][d] ----------------
__global__ __launch_bounds__(256)
void q_transform(const __bf16* __restrict__ q_lin, const float* __restrict__ gam,
                 const float* __restrict__ bet, const int* __restrict__ t_id,
                 __bf16* __restrict__ q_n) {
    const int row  = blockIdx.x * 4 + (threadIdx.x >> 6);
    const int lane = threadIdx.x & 63;
    const int s    = row & (S - 1);
    const int bgh  = row >> 10;
    const int b    = bgh >> 4;
    const int gh   = bgh & 15;
    float x = (float)q_lin[(size_t)(b * S + s) * DIMM + gh * HD + lane];
    const float m = wave64_sum(x) * (1.0f / 64.0f);
    const float d = x - m;
    const float v = wave64_sum(d * d) * (1.0f / 64.0f);
    float y = d * rsqrtf(v + LNEPS) * gam[lane] + bet[lane];
    const float partner = __shfl_xor(y, 1);
    if (lane < PW) {
        const int i = lane >> 1;
        const float theta = expf(-0.57564627324851f * (float)i);
        const float ang = (float)t_id[b * S + s] * theta;
        const float cs = cosf(ang), sn = sinf(ang);
        y = cs * y + sn * ((lane & 1) ? partner : -partner);
    }
    q_n[(size_t)row * HD + lane] = (__bf16)y;
}

// ---------------- k: LayerNorm + rotary -> bf16 [bg][s][d] ----------------
__global__ __launch_bounds__(256)
void k_transform(const __bf16* __restrict__ kv_lin, const float* __restrict__ gam,
                 const float* __restrict__ bet, const int* __restrict__ t_id,
                 __bf16* __restrict__ k_n) {
    const int row  = blockIdx.x * 4 + (threadIdx.x >> 6);
    const int lane = threadIdx.x & 63;
    const int s    = row & (S - 1);
    const int bg   = row >> 10;
    const int b    = bg >> 2;
    const int g    = bg & 3;
    float x = (float)kv_lin[(size_t)(b * S + s) * 512 + g * HD + lane];
    const float m = wave64_sum(x) * (1.0f / 64.0f);
    const float d = x - m;
    const float v = wave64_sum(d * d) * (1.0f / 64.0f);
    float y = d * rsqrtf(v + LNEPS) * gam[lane] + bet[lane];
    const float partner = __shfl_xor(y, 1);
    if (lane < PW) {
        const int i = lane >> 1;
        const float theta = expf(-0.57564627324851f * (float)i);
        const float ang = (float)t_id[b * S + s] * theta;
        const float cs = cosf(ang), sn = sinf(ang);
        y = cs * y + sn * ((lane & 1) ? partner : -partner);
    }
    k_n[(size_t)row * HD + lane] = (__bf16)y;
}

// ---------------- V transpose: bf16 kv_lin[b][s][256+g*64+d] -> bf16 [bg][d][s] ----
__global__ __launch_bounds__(256)
void v_transpose(const __bf16* __restrict__ kv_lin, __bf16* __restrict__ vt) {
    __shared__ float T[64][65];
    const int bg = blockIdx.x >> 4;
    const int s0 = (blockIdx.x & 15) * 64;
    const int b = bg >> 2, g = bg & 3;
    const int tx = threadIdx.x & 63, ty = threadIdx.x >> 6;
    const __bf16* src = kv_lin + ((size_t)(b * S) + s0) * 512 + 256 + g * HD;
    #pragma unroll
    for (int i = 0; i < 16; ++i) {
        const int sp = ty + 4 * i;
        T[sp][tx] = (float)src[(size_t)sp * 512 + tx];
    }
    __syncthreads();
    __bf16* dst = vt + (size_t)bg * HD * S + s0;
    #pragma unroll
    for (int i = 0; i < 16; ++i) {
        const int d = ty + 4 * i;
        dst[(size_t)d * S + tx] = (__bf16)T[tx][d];
    }
}

// ---------------- flash attention v3: 32x32 swapped QK^T, lane-local softmax ----
// 4 waves/block, wave owns 32 q-rows; P redistribution via v_permlane32_swap.
__global__ __launch_bounds__(256, 2)
void flash_mfma(const __bf16* __restrict__ q_n, const __bf16* __restrict__ k_n,
                const __bf16* __restrict__ vt, const float* __restrict__ var_emb,
                const int* __restrict__ qvar, const int* __restrict__ kvar,
                __bf16* __restrict__ attn_h, __bf16* __restrict__ attn_l) {
    const int tid = threadIdx.x;
    const int w = tid >> 6, l = tid & 63;
    const int lq = l & 31;        // q-row (C col) / A row index
    const int h  = l >> 5;        // lane half
    const int qb = blockIdx.x & 7;
    const int bgh = blockIdx.x >> 3;
    const int b = bgh >> 4, gh = bgh & 15;
    const int bg = bgh >> 2;
    const int q0 = qb * 128 + w * 32;

    // Q B-frags: lane holds Q[q=lq][d = 16*dc + 8*h + e]
    const __bf16* qbase = q_n + ((size_t)bgh * S + q0 + lq) * HD + 8 * h;
    bf16x8 qf[4];
    #pragma unroll
    for (int dc = 0; dc < 4; ++dc) qf[dc] = *(const bf16x8*)(qbase + 16 * dc);

    constexpr float L2E = 1.4426950408889634f;
    const int   qv  = qvar[b * S + q0 + lq];
    const float w0l = var_emb[gh] * L2E;
    const float w1l = var_emb[16 + gh] * L2E;
    const float sc2 = SCALE * L2E;

    const __bf16* kbase = k_n + (size_t)bg * S * HD;
    const __bf16* vbase = vt + (size_t)bg * HD * S;
    const int* kvb = kvar + b * S;

    f32x16 OT[2];
    #pragma unroll
    for (int t = 0; t < 2; ++t)
        #pragma unroll
        for (int r = 0; r < 16; ++r) OT[t][r] = 0.0f;
    float mrun = -3.0e38f, lrun = 0.0f;

    // preload K tile 0: A-frag lane holds K[k = 32*ks + lq][d = 16*dc + 8*h + e]
    bf16x8 kf[2][4];
    #pragma unroll
    for (int ks = 0; ks < 2; ++ks)
        #pragma unroll
        for (int dc = 0; dc < 4; ++dc)
            kf[ks][dc] = *(const bf16x8*)(kbase + (size_t)(32 * ks + lq) * HD + 16 * dc + 8 * h);

    for (int k0 = 0; k0 < S; k0 += 64) {
        // V A-frags for current tile: lane holds V^T[32*T + lq][k0 + 32*ks + 16*kc + 8*h + e]
        bf16x8 vf[2][2][2];
        #pragma unroll
        for (int t = 0; t < 2; ++t)
            #pragma unroll
            for (int ks = 0; ks < 2; ++ks)
                #pragma unroll
                for (int kc = 0; kc < 2; ++kc)
                    vf[t][ks][kc] = *(const bf16x8*)
                        (vbase + (size_t)(32 * t + lq) * S + k0 + 32 * ks + 16 * kc + 8 * h);
        // kvar for this lane's 32 k slots: k = 32*ks + 8*j + 4*h + {0..3}
        int kvi[2][16];
        #pragma unroll
        for (int ks = 0; ks < 2; ++ks)
            #pragma unroll
            for (int j = 0; j < 4; ++j)
                *(int4*)&kvi[ks][4 * j] = *(const int4*)(kvb + k0 + 32 * ks + 8 * j + 4 * h);

        // swapped QK^T: D[k-row][q-col]; lane gets S[k = 32ks + (r&3)+8(r>>2)+4h][q=lq]
        f32x16 st[2];
        #pragma unroll
        for (int ks = 0; ks < 2; ++ks) {
            f32x16 acc;
            #pragma unroll
            for (int r = 0; r < 16; ++r) acc[r] = 0.0f;
            #pragma unroll
            for (int dc = 0; dc < 4; ++dc)
                acc = __builtin_amdgcn_mfma_f32_32x32x16_bf16(kf[ks][dc], qf[dc], acc, 0, 0, 0);
            st[ks] = acc;
        }

        // prefetch next K tile (hidden under softmax + PV)
        const int kn = (k0 + 64 < S) ? k0 + 64 : 0;
        #pragma unroll
        for (int ks = 0; ks < 2; ++ks)
            #pragma unroll
            for (int dc = 0; dc < 4; ++dc)
                kf[ks][dc] = *(const bf16x8*)
                    (kbase + (size_t)(kn + 32 * ks + lq) * HD + 16 * dc + 8 * h);

        // bias + scale (log2 domain) + in-lane max over this lane's 32 slots
        float tmax = -3.0e38f;
        #pragma unroll
        for (int ks = 0; ks < 2; ++ks)
            #pragma unroll
            for (int r = 0; r < 16; ++r) {
                st[ks][r] = fmaf(st[ks][r], sc2, (qv == kvi[ks][r]) ? w1l : w0l);
                tmax = fmaxf(tmax, st[ks][r]);
            }
        tmax = fmaxf(tmax, __shfl_xor(tmax, 32));   // combine halves (same q)

        // defer-max (THR = 8 nats = 11.54 log2)
        float mref = mrun;
        if (!__all(tmax - mrun <= 11.54f)) {
            const float mnew = fmaxf(mrun, tmax);
            const float alpha = exp2f(mrun - mnew);   // lane-local (q = lq)
            #pragma unroll
            for (int t = 0; t < 2; ++t)
                #pragma unroll
                for (int r = 0; r < 16; ++r) OT[t][r] *= alpha;
            lrun *= alpha;
            mrun = mnew; mref = mnew;
        }

        // P = exp2(st - mref); pack pairs (consecutive k) to bf16 u32s
        float psum = 0.0f;
        unsigned int u[2][8];
        #pragma unroll
        for (int ks = 0; ks < 2; ++ks)
            #pragma unroll
            for (int jj = 0; jj < 8; ++jj) {
                const float p0 = exp2f(st[ks][2 * jj]     - mref);
                const float p1 = exp2f(st[ks][2 * jj + 1] - mref);
                psum += p0 + p1;
                asm("v_cvt_pk_bf16_f32 %0, %1, %2" : "=v"(u[ks][jj]) : "v"(p0), "v"(p1));
            }
        psum += __shfl_xor(psum, 32);
        lrun += psum;

        // P redistribution: swap(u_a, u_b) -> both B-frag words at once
        uint4 F[2][2];
        #pragma unroll
        for (int ks = 0; ks < 2; ++ks) {
            unsigned a0 = u[ks][0], b0 = u[ks][2];
            unsigned a1 = u[ks][1], b1 = u[ks][3];
            asm("v_permlane32_swap_b32 %0, %1" : "+v"(a0), "+v"(b0));
            asm("v_permlane32_swap_b32 %0, %1" : "+v"(a1), "+v"(b1));
            F[ks][0] = make_uint4(a0, a1, b0, b1);
            unsigned a2 = u[ks][4], b2 = u[ks][6];
            unsigned a3 = u[ks][5], b3 = u[ks][7];
            asm("v_permlane32_swap_b32 %0, %1" : "+v"(a2), "+v"(b2));
            asm("v_permlane32_swap_b32 %0, %1" : "+v"(a3), "+v"(b3));
            F[ks][1] = make_uint4(a2, a3, b2, b3);
        }

        // PV: O^T[d][q] += V^T[d][k] * P^T[k][q]
        #pragma unroll
        for (int t = 0; t < 2; ++t)
            #pragma unroll
            for (int ks = 0; ks < 2; ++ks)
                #pragma unroll
                for (int kc = 0; kc < 2; ++kc)
                    OT[t] = __builtin_amdgcn_mfma_f32_32x32x16_bf16(
                        vf[t][ks][kc], __builtin_bit_cast(bf16x8, F[ks][kc]), OT[t], 0, 0, 0);
    }

    // epilogue: all lane-local; write 4-consecutive-d groups as 8B stores
    const float linv = 1.0f / lrun;
    __bf16* oh = attn_h + (size_t)(b * S + q0 + lq) * DIMM + gh * HD;
    __bf16* ol = attn_l + (size_t)(b * S + q0 + lq) * DIMM + gh * HD;
    #pragma unroll
    for (int t = 0; t < 2; ++t)
        #pragma unroll
        for (int j = 0; j < 4; ++j) {
            const int d0 = 32 * t + 8 * j + 4 * h;
            unsigned short hv[4], lv[4];
            #pragma unroll
            for (int c = 0; c < 4; ++c) {
                const float v = OT[t][4 * j + c] * linv;
                const __bf16 hb = (__bf16)v;
                hv[c] = __builtin_bit_cast(unsigned short, hb);
                lv[c] = __builtin_bit_cast(unsigned short, (__bf16)(v - (float)hb));
            }
            *(ushort4*)(oh + d0) = make_ushort4(hv[0], hv[1], hv[2], hv[3]);
            *(ushort4*)(ol + d0) = make_ushort4(lv[0], lv[1], lv[2], lv[3]);
        }
}

extern "C" void kernel_launch(void* const* d_in, const int* in_sizes, int n_in,
                              void* d_out, int out_size, void* d_ws, size_t ws_size,
                              hipStream_t stream) {
    const float* x     = (const float*)d_in[0];
    const float* kv    = (const float*)d_in[1];
    const float* q_w   = (const float*)d_in[2];
    const float* q_b   = (const float*)d_in[3];
    const float* k_w   = (const float*)d_in[4];
    const float* k_b   = (const float*)d_in[5];
    const float* v_w   = (const float*)d_in[6];
    const float* v_b   = (const float*)d_in[7];
    const float* o_w   = (const float*)d_in[8];
    const float* o_b   = (const float*)d_in[9];
    const float* qn_g  = (const float*)d_in[10];
    const float* qn_b  = (const float*)d_in[11];
    const float* kn_g  = (const float*)d_in[12];
    const float* kn_b  = (const float*)d_in[13];
    const float* vemb  = (const float*)d_in[14];
    const int*   qvar  = (const int*)d_in[15];
    const int*   kvar  = (const int*)d_in[16];
    const int*   qtime = (const int*)d_in[17];
    const int*   ktime = (const int*)d_in[18];
    float* out = (float*)d_out;
    char*  W   = (char*)d_ws;

    const size_t MB = 1u << 20;
    __bf16* xh     = (__bf16*)(W);                 // 0-8   -> attn_h
    __bf16* kvh    = (__bf16*)(W + 8 * MB);        // 8-16  -> attn_l
    __bf16* q_lin  = (__bf16*)(W + 16 * MB);       // 16-24
    __bf16* kv_lin = (__bf16*)(W + 24 * MB);       // 24-28
    __bf16* q_nb   = (__bf16*)(W + 28 * MB);       // 28-36 (overlays qwh/kvwh/kvb)
    __bf16* qwh    = (__bf16*)(W + 28 * MB);
    __bf16* kvwh   = (__bf16*)(W + 30 * MB);
    float*  kvb    = (float*)(W + 31 * MB);
    __bf16* k_nb   = (__bf16*)(W + 36 * MB);       // 36-38
    __bf16* vtb    = (__bf16*)(W + 38 * MB);       // 38-40
    __bf16* owh    = (__bf16*)(W + 40 * MB);       // 40-42
    __bf16* owl    = (__bf16*)(W + 42 * MB);       // 42-44
    __bf16* attn_h = xh;
    __bf16* attn_l = kvh;

    dim3 blk(256);

    cvt_all<<<5377, blk, 0, stream>>>(x, kv, q_w, k_w, v_w, o_w, k_b, v_b,
                                      xh, kvh, qwh, kvwh, owh, owl, kvb);

    gemm_mfma<128, false, true><<<dim3(8, 32), blk, 0, stream>>>(
        xh, nullptr, qwh, nullptr, q_b, (void*)q_lin, 1024, 1024);
    gemm_mfma<64, false, true><<<dim3(8, 32), blk, 0, stream>>>(
        kvh, nullptr, kvwh, nullptr, kvb, (void*)kv_lin, 512, 1024);

    q_transform<<<(4 * G * HPG * S) / 4, blk, 0, stream>>>(q_lin, qn_g, qn_b, qtime, q_nb);
    k_transform<<<(4 * G * S) / 4,       blk, 0, stream>>>(kv_lin, kn_g, kn_b, ktime, k_nb);
    v_transpose<<<16 * 16,               blk, 0, stream>>>(kv_lin, vtb);

    flash_mfma<<<64 * 8, blk, 0, stream>>>(
        q_nb, k_nb, vtb, vemb, qvar, kvar, attn_h, attn_l);

    gemm_mfma<128, true, false><<<dim3(8, 32), blk, 0, stream>>>(
        attn_h, attn_l, owh, owl, o_b, (void*)out, 1024, 1024);
}